// Round 3
// baseline (23.985 us; speedup 1.0000x reference)
//
#include <hip/hip_runtime.h>

namespace {
constexpr int Bc  = 16;
constexpr int Nc  = 96;
constexpr int KRc = 16;
constexpr int KAc = 8;
constexpr int NOUT = KRc + KAc;            // 24
constexpr int NNb   = Nc - 1;              // 95 neighbors per atom
constexpr int NRr   = (NNb - 1) / 2;       // 47 round-robin rounds
constexpr int NPAIR = NRr * NNb;           // 4465 unordered pairs
constexpr float RCRf  = 5.2f;
constexpr float RCAf  = 3.5f;
constexpr float L2E   = 1.4426950408889634f;
}

// cos(2*pi*rev) via HW trans ops; rev >= 0 here
__device__ __forceinline__ float cos_rev(float rev) {
    return __builtin_amdgcn_cosf(__builtin_amdgcn_fractf(rev));
}

// SPLIT = sub-blocks per atom. SPLIT==1 writes out directly; SPLIT==2 writes
// per-half partials (all 24 features) to ws[(bi*2+h)*24 + f].
template<int SPLIT>
__global__ __launch_bounds__(256, 8) void ani_feat_kernel(
    const float* __restrict__ coords,      // (B,N,3)
    const int*   __restrict__ atom_types,  // (N,)
    const float* __restrict__ EtaR,        // (T,KR)
    const float* __restrict__ ShfR,        // (T,KR)
    const float* __restrict__ Zeta,        // (T,KA)
    const float* __restrict__ EtaA,        // (T,KA)
    float* __restrict__ dst)
{
    const int blk = blockIdx.x;
    const int bi  = blk / SPLIT;           // b*N + i
    const int h   = blk - bi * SPLIT;      // sub-block 0..SPLIT-1
    const int b   = bi / Nc;
    const int i   = bi - b * Nc;
    const int t   = threadIdx.x;

    __shared__ float4 un[NNb];             // unit vec + distance d
    __shared__ float  sfa[NNb];            // angular cutoff f(d; RCA)
    __shared__ float  sdr[NNb];            // d
    __shared__ float  sfr[NNb];            // radial cutoff f(d; RCR)
    __shared__ float  pr[16][KRc];         // radial partials
    __shared__ float  red[4][KAc];         // angular wave partials

    const int ti = atom_types[i];

    if (t < NNb) {
        const float* cb = coords + (size_t)(b * Nc) * 3;
        int j = t + (t >= i);
        float dx = cb[i*3+0] - cb[j*3+0];
        float dy = cb[i*3+1] - cb[j*3+1];
        float dz = cb[i*3+2] - cb[j*3+2];
        float d2 = dx*dx + dy*dy + dz*dz;
        float d  = __builtin_amdgcn_sqrtf(d2);
        float inv = 1.0f / d;
        un[t]  = make_float4(dx*inv, dy*inv, dz*inv, d);
        sdr[t] = d;
        sfa[t] = fmaf(cos_rev(d * (0.5f / RCAf)), 0.5f, 0.5f);
        sfr[t] = fmaf(cos_rev(d * (0.5f / RCRf)), 0.5f, 0.5f);
    }

    // ---- angular parameters + uniform fast-path detection (block-uniform) ----
    float zek[KAc], c1k[KAc], eaL[KAc];
#pragma unroll
    for (int k = 0; k < KAc; ++k) {
        float z = Zeta[ti * KAc + k];
        zek[k] = z;
        c1k[k] = 1.0f - z;
        eaL[k] = EtaA[ti * KAc + k] * L2E;
    }
    bool zuni = true;
#pragma unroll
    for (int k = 1; k < KAc; ++k) zuni = zuni && (zek[k] == zek[0]);
    const float dL = eaL[1] - eaL[0];
    bool arith = true;
#pragma unroll
    for (int k = 2; k < KAc; ++k)
        arith = arith && (fabsf(eaL[k] - (eaL[0] + dL * (float)k)) <=
                          1e-5f * fabsf(eaL[k]) + 1e-7f);
    const bool fastu = zuni && arith;
    const bool z32   = (zek[0] == 32.0f);
    const float z0 = zek[0], c10 = c1k[0], ea0 = eaL[0];
    const float p21z = __builtin_amdgcn_exp2f(c10);   // 2^(1-z)

    __syncthreads();

    // ---- radial G2: k per lane-of-16, register accumulate ----
    {
        const int k = t & 15, g = t >> 4;
        float er  = EtaR[ti * KRc + k];
        float sr  = ShfR[ti * KRc + k];
        float erL = -er * L2E;
        float acc = 0.0f;
        for (int jj = g + 16 * h; jj < NNb; jj += 16 * SPLIT) {
            float dd = sdr[jj] - sr;
            acc += __builtin_amdgcn_exp2f(erL * dd * dd) * sfr[jj];
        }
        pr[g][k] = acc;
    }

    // ---- angular G3: round-robin pairs, incremental index, masked tail ----
    float acc[KAc];
#pragma unroll
    for (int k = 0; k < KAc; ++k) acc[k] = 0.0f;

    constexpr int STR   = 256 * SPLIT;
    constexpr int DR    = STR / NNb;
    constexpr int DJ    = STR - DR * NNb;
    constexpr int ITERS = (NPAIR + STR - 1) / STR;

    {
        int idx0 = h * 256 + t;
        int rr = idx0 / NNb;               // small, compiler magic-mul
        int j  = idx0 - rr * NNb;

        if (fastu && z32) {
#pragma unroll 3
            for (int it = 0; it < ITERS; ++it) {
                int j2 = j + rr + 1; if (j2 >= NNb) j2 -= NNb;
                float live = (rr < NRr) ? 1.0f : 0.0f;
                float4 A  = un[j];
                float4 Bv = un[j2];
                float faf = sfa[j] * sfa[j2];

                float cosv = fmaf(A.x, Bv.x, fmaf(A.y, Bv.y, A.z * Bv.z));
                float sAB  = fmaf(A.w, A.w, Bv.w * Bv.w);
                float d23sq = fmaxf(fmaf(-2.0f * A.w * Bv.w, cosv, sAB), 0.0f);
                float d23 = __builtin_amdgcn_sqrtf(d23sq);
                float f23 = fmaf(cos_rev(d23 * (0.5f / RCAf)), 0.5f, 0.5f);
                float fprod = faf * f23 * live;
                float s  = sAB + d23sq;
                float tt = fmaxf(1.0f + cosv, 0.0f);

                float t2 = tt*tt, t4 = t2*t2, t8 = t4*t4, t16 = t8*t8;
                float P  = t16 * t16 * p21z;           // tt^32 * 2^(1-32)
                float F  = P * fprod;
                float e0 = __builtin_amdgcn_exp2f(-ea0 * s);
                float q  = __builtin_amdgcn_exp2f(-dL * s);
                float q2 = q * q;
                float e1 = e0 * q,  e2 = e0 * q2, e3 = e1 * q2;
                float e4 = e2 * q2, e5 = e3 * q2, e6 = e4 * q2, e7 = e5 * q2;
                acc[0] = fmaf(F, e0, acc[0]);
                acc[1] = fmaf(F, e1, acc[1]);
                acc[2] = fmaf(F, e2, acc[2]);
                acc[3] = fmaf(F, e3, acc[3]);
                acc[4] = fmaf(F, e4, acc[4]);
                acc[5] = fmaf(F, e5, acc[5]);
                acc[6] = fmaf(F, e6, acc[6]);
                acc[7] = fmaf(F, e7, acc[7]);

                j += DJ; rr += DR; if (j >= NNb) { j -= NNb; ++rr; }
            }
        } else if (fastu) {
#pragma unroll 2
            for (int it = 0; it < ITERS; ++it) {
                int j2 = j + rr + 1; if (j2 >= NNb) j2 -= NNb;
                float live = (rr < NRr) ? 1.0f : 0.0f;
                float4 A  = un[j];
                float4 Bv = un[j2];
                float faf = sfa[j] * sfa[j2];

                float cosv = fmaf(A.x, Bv.x, fmaf(A.y, Bv.y, A.z * Bv.z));
                float sAB  = fmaf(A.w, A.w, Bv.w * Bv.w);
                float d23sq = fmaxf(fmaf(-2.0f * A.w * Bv.w, cosv, sAB), 0.0f);
                float d23 = __builtin_amdgcn_sqrtf(d23sq);
                float f23 = fmaf(cos_rev(d23 * (0.5f / RCAf)), 0.5f, 0.5f);
                float fprod = faf * f23 * live;
                float s  = sAB + d23sq;
                float tt = fmaxf(1.0f + cosv, 0.0f);

                float P = __builtin_amdgcn_exp2f(
                              fmaf(z0, __builtin_amdgcn_logf(tt), c10));
                float F  = P * fprod;
                float e0 = __builtin_amdgcn_exp2f(-ea0 * s);
                float q  = __builtin_amdgcn_exp2f(-dL * s);
                float q2 = q * q;
                float e1 = e0 * q,  e2 = e0 * q2, e3 = e1 * q2;
                float e4 = e2 * q2, e5 = e3 * q2, e6 = e4 * q2, e7 = e5 * q2;
                acc[0] = fmaf(F, e0, acc[0]);
                acc[1] = fmaf(F, e1, acc[1]);
                acc[2] = fmaf(F, e2, acc[2]);
                acc[3] = fmaf(F, e3, acc[3]);
                acc[4] = fmaf(F, e4, acc[4]);
                acc[5] = fmaf(F, e5, acc[5]);
                acc[6] = fmaf(F, e6, acc[6]);
                acc[7] = fmaf(F, e7, acc[7]);

                j += DJ; rr += DR; if (j >= NNb) { j -= NNb; ++rr; }
            }
        } else {
            for (int it = 0; it < ITERS; ++it) {
                int j2 = j + rr + 1; if (j2 >= NNb) j2 -= NNb;
                float live = (rr < NRr) ? 1.0f : 0.0f;
                float4 A  = un[j];
                float4 Bv = un[j2];
                float faf = sfa[j] * sfa[j2];

                float cosv = fmaf(A.x, Bv.x, fmaf(A.y, Bv.y, A.z * Bv.z));
                float sAB  = fmaf(A.w, A.w, Bv.w * Bv.w);
                float d23sq = fmaxf(fmaf(-2.0f * A.w * Bv.w, cosv, sAB), 0.0f);
                float d23 = __builtin_amdgcn_sqrtf(d23sq);
                float f23 = fmaf(cos_rev(d23 * (0.5f / RCAf)), 0.5f, 0.5f);
                float fprod = faf * f23 * live;
                float s  = sAB + d23sq;
                float tt = fmaxf(1.0f + cosv, 0.0f);
                float l2 = __builtin_amdgcn_logf(tt);
#pragma unroll
                for (int k = 0; k < KAc; ++k) {
                    float E = fmaf(zek[k], l2, c1k[k]);
                    E = fmaf(-eaL[k], s, E);
                    acc[k] += __builtin_amdgcn_exp2f(E) * fprod;
                }
                j += DJ; rr += DR; if (j >= NNb) { j -= NNb; ++rr; }
            }
        }
    }

    // ---- reductions ----
    const int lane = t & 63, wave = t >> 6;
#pragma unroll
    for (int k = 0; k < KAc; ++k) {
        float v = acc[k];
#pragma unroll
        for (int off = 32; off; off >>= 1) v += __shfl_xor(v, off, 64);
        if (lane == 0) red[wave][k] = v;
    }
    __syncthreads();

    float* o = (SPLIT == 1) ? (dst + (size_t)bi * NOUT)
                            : (dst + (size_t)(bi * SPLIT + h) * NOUT);
    if (t < KAc) {
        o[KRc + t] = red[0][t] + red[1][t] + red[2][t] + red[3][t];
    }
    if (t < KRc) {
        float s = 0.0f;
#pragma unroll
        for (int g = 0; g < 16; ++g) s += pr[g][t];
        o[t] = s;
    }
}

__global__ __launch_bounds__(256) void combine2_kernel(
    const float* __restrict__ ws, float* __restrict__ out, int n)
{
    int e = blockIdx.x * 256 + threadIdx.x;
    if (e < n) {
        int bi = e / NOUT, f = e - bi * NOUT;
        out[e] = ws[(bi * 2) * NOUT + f] + ws[(bi * 2 + 1) * NOUT + f];
    }
}

extern "C" void kernel_launch(void* const* d_in, const int* in_sizes, int n_in,
                              void* d_out, int out_size, void* d_ws, size_t ws_size,
                              hipStream_t stream) {
    const float* coords     = (const float*)d_in[0];
    const int*   atom_types = (const int*)d_in[1];
    const float* EtaR       = (const float*)d_in[2];
    const float* ShfR       = (const float*)d_in[3];
    const float* Zeta       = (const float*)d_in[4];
    const float* EtaA       = (const float*)d_in[5];
    float* out = (float*)d_out;

    const size_t ws_need = (size_t)Bc * Nc * 2 * NOUT * sizeof(float);
    if (ws_size >= ws_need) {
        ani_feat_kernel<2><<<dim3(Bc * Nc * 2), dim3(256), 0, stream>>>(
            coords, atom_types, EtaR, ShfR, Zeta, EtaA, (float*)d_ws);
        int n = Bc * Nc * NOUT;
        combine2_kernel<<<dim3((n + 255) / 256), dim3(256), 0, stream>>>(
            (const float*)d_ws, out, n);
    } else {
        ani_feat_kernel<1><<<dim3(Bc * Nc), dim3(256), 0, stream>>>(
            coords, atom_types, EtaR, ShfR, Zeta, EtaA, out);
    }
}